// Round 2
// baseline (431.844 us; speedup 1.0000x reference)
//
#include <hip/hip_runtime.h>

#define DIM 128
#define MOMENTUM 0.5f

typedef float v4 __attribute__((ext_vector_type(4)));

// Grid-stride copy, 4-way unrolled with independent nontemporal float4
// loads/stores. Target: m13 copy ceiling (~6.3 TB/s -> ~81 us for 512 MB).
// Previous plain grid-stride version measured ~4.6 TB/s (latency-limited:
// one outstanding load per thread iteration). 4 independent loads per
// iteration gives the MLP needed to cover ~900-cycle HBM latency.
__global__ __launch_bounds__(256) void bank_copy_f4(const v4* __restrict__ src,
                                                    v4* __restrict__ dst,
                                                    long long n4) {
    const long long stride = (long long)gridDim.x * blockDim.x;
    long long i = (long long)blockIdx.x * blockDim.x + threadIdx.x;

    for (; i + 3 * stride < n4; i += 4 * stride) {
        v4 a = __builtin_nontemporal_load(&src[i]);
        v4 b = __builtin_nontemporal_load(&src[i + stride]);
        v4 c = __builtin_nontemporal_load(&src[i + 2 * stride]);
        v4 d = __builtin_nontemporal_load(&src[i + 3 * stride]);
        __builtin_nontemporal_store(a, &dst[i]);
        __builtin_nontemporal_store(b, &dst[i + stride]);
        __builtin_nontemporal_store(c, &dst[i + 2 * stride]);
        __builtin_nontemporal_store(d, &dst[i + 3 * stride]);
    }
    for (; i < n4; i += stride)
        __builtin_nontemporal_store(__builtin_nontemporal_load(&src[i]), &dst[i]);
}

// One wave (64 lanes) per row; each lane owns 2 consecutive floats.
// EMA source rows are read from `memory` (the input), NOT from `out`:
// values are identical (copy precedes update; update rows are only
// overwritten here), and this avoids re-reading lines we just streamed
// with nontemporal stores.
__global__ void FeatureBank_update_rows(const float* __restrict__ x,
                                        const int* __restrict__ y,
                                        const float* __restrict__ memory,
                                        float* __restrict__ out,
                                        int batch) {
    const int lane = threadIdx.x & 63;
    const int wave = threadIdx.x >> 6;
    const int row = blockIdx.x * (blockDim.x >> 6) + wave;
    if (row >= batch) return;

    const long long dst = (long long)y[row] * DIM;

    const float2 xv = ((const float2*)(x + (long long)row * DIM))[lane];
    const float2 mv = ((const float2*)(memory + dst))[lane];

    float2 w;
    w.x = MOMENTUM * mv.x + (1.0f - MOMENTUM) * xv.x;
    w.y = MOMENTUM * mv.y + (1.0f - MOMENTUM) * xv.y;

    float ss = w.x * w.x + w.y * w.y;
    // wave64 butterfly reduction
    #pragma unroll
    for (int off = 32; off > 0; off >>= 1)
        ss += __shfl_xor(ss, off, 64);

    const float inv = rsqrtf(ss);
    float2 o;
    o.x = w.x * inv;
    o.y = w.y * inv;
    ((float2*)(out + dst))[lane] = o;
}

extern "C" void kernel_launch(void* const* d_in, const int* in_sizes, int n_in,
                              void* d_out, int out_size, void* d_ws, size_t ws_size,
                              hipStream_t stream) {
    const float* x      = (const float*)d_in[0];
    const int*   y      = (const int*)d_in[1];
    const float* memory = (const float*)d_in[2];
    float*       out    = (float*)d_out;

    const int batch = in_sizes[1];                 // 4096
    const long long n4 = (long long)out_size / 4;  // 16M float4

    // Bulk copy memory -> out at HBM rate.
    bank_copy_f4<<<2048, 256, 0, stream>>>((const v4*)memory, (v4*)out, n4);

    // Update the touched rows in place.
    const int waves_per_block = 4;                 // 256 threads
    const int block = 64 * waves_per_block;
    const int grid = (batch + waves_per_block - 1) / waves_per_block;
    FeatureBank_update_rows<<<grid, block, 0, stream>>>(x, y, memory, out, batch);
}

// Round 3
// 419.660 us; speedup vs baseline: 1.0290x; 1.0290x over previous
//
#include <hip/hip_runtime.h>

#define DIM 128
#define MOMENTUM 0.5f

// One wave (64 lanes) per row; each lane owns 2 consecutive floats.
// EMA source rows read from `memory` (the input), not `out`: values are
// identical (copy precedes update on the stream; updated rows are only
// written here), and this keeps the update independent of the copy's
// cache behavior.
//
// NOTE (rounds 0-2 evidence): the bulk memory->out copy is fastest via
// hipMemcpyAsync (418.5 us total) — shader copies (plain grid-stride float4
// r1, 4-way-unrolled nontemporal r2) both measured ~430-432 us, insensitive
// to implementation. ~320 us of the timed region is harness poison fills
// (1.024 GB fillBufferAligned @ 6.4 TB/s, visible in every rocprof top-5);
// the copy floor is 512 MB @ 6.3 TB/s ~= 81 us; update is ~4 us.
__global__ void FeatureBank_update_rows(const float* __restrict__ x,
                                        const int* __restrict__ y,
                                        const float* __restrict__ memory,
                                        float* __restrict__ out,
                                        int batch) {
    const int lane = threadIdx.x & 63;
    const int wave = threadIdx.x >> 6;
    const int row = blockIdx.x * (blockDim.x >> 6) + wave;
    if (row >= batch) return;

    const long long dst = (long long)y[row] * DIM;

    const float2 xv = ((const float2*)(x + (long long)row * DIM))[lane];
    const float2 mv = ((const float2*)(memory + dst))[lane];

    float2 w;
    w.x = MOMENTUM * mv.x + (1.0f - MOMENTUM) * xv.x;
    w.y = MOMENTUM * mv.y + (1.0f - MOMENTUM) * xv.y;

    float ss = w.x * w.x + w.y * w.y;
    // wave64 butterfly reduction
    #pragma unroll
    for (int off = 32; off > 0; off >>= 1)
        ss += __shfl_xor(ss, off, 64);

    const float inv = rsqrtf(ss);
    float2 o;
    o.x = w.x * inv;
    o.y = w.y * inv;
    ((float2*)(out + dst))[lane] = o;
}

extern "C" void kernel_launch(void* const* d_in, const int* in_sizes, int n_in,
                              void* d_out, int out_size, void* d_ws, size_t ws_size,
                              hipStream_t stream) {
    const float* x      = (const float*)d_in[0];
    const int*   y      = (const int*)d_in[1];
    const float* memory = (const float*)d_in[2];
    float*       out    = (float*)d_out;

    const int batch = in_sizes[1];                          // 4096
    const size_t bytes = (size_t)out_size * sizeof(float);  // 256 MB

    // Bulk copy memory -> out (runtime D2D path: best measured, r0 = 418.5 us).
    hipMemcpyAsync(out, memory, bytes, hipMemcpyDeviceToDevice, stream);

    // Update the touched rows in place.
    const int waves_per_block = 4;                          // 256 threads
    const int block = 64 * waves_per_block;
    const int grid = (batch + waves_per_block - 1) / waves_per_block;
    FeatureBank_update_rows<<<grid, block, 0, stream>>>(x, y, memory, out, batch);
}